// Round 8
// baseline (17970.422 us; speedup 1.0000x reference)
//
#include <hip/hip_runtime.h>
#include <hip/hip_fp16.h>
#include <math.h>

#define Bsz 64
#define Tsz 1024
#define Isz 128
#define Hsz 512
#define KH  256   // H/2
#define Osz 10

// ---------------------------------------------------------------------------
// Register-tiled fp32 GEMM: C[M,N] = A[M,K] @ Bw[K,N] + bias[N]
// ---------------------------------------------------------------------------
__global__ __launch_bounds__(256) void gemm_bias_kernel(
    const float* __restrict__ A, const float* __restrict__ Bw,
    const float* __restrict__ bias, float* __restrict__ C,
    int M, int N, int K)
{
  __shared__ float As[32][68];   // [k][m], padded
  const int tid = threadIdx.x;
  const int m0 = blockIdx.x * 64;
  const int n0 = blockIdx.y * 128;
  const int ty = tid >> 5, tx = tid & 31;

  float acc[8][4] = {{0.f}};

  for (int kk = 0; kk < K; kk += 32) {
    __syncthreads();
#pragma unroll
    for (int i = tid; i < 64 * 32; i += 256) {
      int m = i >> 5, k = i & 31;
      As[k][m] = A[(size_t)(m0 + m) * K + kk + k];
    }
    __syncthreads();
#pragma unroll
    for (int k = 0; k < 32; ++k) {
      const float4 bv = *(const float4*)(&Bw[(size_t)(kk + k) * N + n0 + tx * 4]);
      float a[8];
#pragma unroll
      for (int i = 0; i < 8; ++i) a[i] = As[k][ty * 8 + i];
#pragma unroll
      for (int i = 0; i < 8; ++i) {
        acc[i][0] = fmaf(a[i], bv.x, acc[i][0]);
        acc[i][1] = fmaf(a[i], bv.y, acc[i][1]);
        acc[i][2] = fmaf(a[i], bv.z, acc[i][2]);
        acc[i][3] = fmaf(a[i], bv.w, acc[i][3]);
      }
    }
  }

  const float4 bb = *(const float4*)(&bias[n0 + tx * 4]);
#pragma unroll
  for (int i = 0; i < 8; ++i) {
    float4 v;
    v.x = acc[i][0] + bb.x; v.y = acc[i][1] + bb.y;
    v.z = acc[i][2] + bb.z; v.w = acc[i][3] + bb.w;
    *(float4*)(&C[(size_t)(m0 + ty * 8 + i) * N + n0 + tx * 4]) = v;
  }
}

// ---------------------------------------------------------------------------
// Wc = W_in @ W1a  (128x512 @ 512x256 -> 128x256), one block per row i.
// ---------------------------------------------------------------------------
__global__ __launch_bounds__(256) void wc_kernel(
    const float* __restrict__ W_in, const float* __restrict__ W1a,
    float* __restrict__ Wc)
{
  __shared__ float row[Hsz];
  const int i = blockIdx.x, c = threadIdx.x;
  for (int h = c; h < Hsz; h += 256) row[h] = W_in[(size_t)i * Hsz + h];
  __syncthreads();
  float acc = 0.f;
#pragma unroll 8
  for (int h = 0; h < Hsz; ++h)
    acc = fmaf(row[h], W1a[(size_t)h * KH + c], acc);
  Wc[(size_t)i * KH + c] = acc;
}

// b_U = b_in @ W1a + b_tau1  (256)
__global__ __launch_bounds__(256) void bu_kernel(
    const float* __restrict__ b_in, const float* __restrict__ W1a,
    const float* __restrict__ b_tau1, float* __restrict__ bU)
{
  const int c = threadIdx.x;
  float acc = b_tau1[c];
#pragma unroll 8
  for (int h = 0; h < Hsz; ++h)
    acc = fmaf(b_in[h], W1a[(size_t)h * KH + c], acc);
  bU[c] = acc;
}

// ---------------------------------------------------------------------------
// i8 dot4
// ---------------------------------------------------------------------------
__device__ __forceinline__ int dot4i8(int a, int b, int acc) {
#if __has_builtin(__builtin_amdgcn_sdot4)
  return __builtin_amdgcn_sdot4(a, b, acc, false);
#else
  acc += ((a << 24) >> 24) * ((b << 24) >> 24);
  acc += ((a << 16) >> 24) * ((b << 16) >> 24);
  acc += ((a << 8)  >> 24) * ((b << 8)  >> 24);
  acc += (a >> 24) * (b >> 24);
  return acc;
#endif
}

// ---------------------------------------------------------------------------
// Quantizer layouts: [G groups x C cols] i8; group g, dword di, byte e covers
// source k = 16g + 4di + e; flat dword index = g*(C*4)+c*4+di.
// ---------------------------------------------------------------------------

__global__ __launch_bounds__(256) void drive_scale_kernel(
    const float* __restrict__ W_rec, float* __restrict__ CS0)
{
  const int j = blockIdx.x * 256 + threadIdx.x;  // 512
  float m = 0.f;
  for (int k = 0; k < Hsz; ++k)
    m = fmaxf(m, fabsf(W_rec[(size_t)j * Hsz + k]));
  CS0[j] = m;
}

__global__ __launch_bounds__(256) void drive_quant_kernel(
    const float* __restrict__ W_rec, const float* __restrict__ CS0,
    unsigned* __restrict__ Q0)
{
  int i = blockIdx.x * 256 + threadIdx.x;  // 65536 dwords
  if (i >= 32 * Hsz * 4) return;
  int di = i & 3, j = (i >> 2) & 511, g = i >> 11;
  int k0 = 16 * g + 4 * di;
  float ma = CS0[j];
  float r = (ma > 0.f) ? (127.f / ma) : 0.f;
  unsigned out = 0;
#pragma unroll
  for (int e = 0; e < 4; ++e) {
    int q = __float2int_rn(W_rec[(size_t)j * Hsz + k0 + e] * r);
    out |= ((unsigned)(q & 255)) << (8 * e);
  }
  Q0[i] = out;
}

__global__ __launch_bounds__(256) void tau1_scale_kernel(
    const float* __restrict__ W1b, float* __restrict__ CS1)
{
  const int c = threadIdx.x;  // 256
  float m = 0.f;
  for (int j = 0; j < Hsz; ++j)
    m = fmaxf(m, fabsf(W1b[(size_t)j * KH + c]));
  CS1[c] = m;
}

__global__ __launch_bounds__(256) void tau1_quant_kernel(
    const float* __restrict__ W1b, const float* __restrict__ CS1,
    unsigned* __restrict__ Q1)
{
  int i = blockIdx.x * 256 + threadIdx.x;  // 32768 dwords
  if (i >= 32 * KH * 4) return;
  int di = i & 3, c = (i >> 2) & 255, g = i >> 10;
  int j0 = 16 * g + 4 * di;
  float ma = CS1[c];
  float r = (ma > 0.f) ? (127.f / ma) : 0.f;
  unsigned out = 0;
#pragma unroll
  for (int e = 0; e < 4; ++e) {
    int q = __float2int_rn(W1b[(size_t)(j0 + e) * KH + c] * r);
    out |= ((unsigned)(q & 255)) << (8 * e);
  }
  Q1[i] = out;
}

__global__ __launch_bounds__(256) void tau2_scale_kernel(
    const float* __restrict__ W_tau2, float* __restrict__ CS2)
{
  const int j = blockIdx.x * 256 + threadIdx.x;  // 512
  float m = 0.f;
  for (int k = 0; k < KH; ++k)
    m = fmaxf(m, fabsf(W_tau2[(size_t)k * Hsz + j]));
  CS2[j] = m;
}

__global__ __launch_bounds__(256) void tau2_quant_kernel(
    const float* __restrict__ W_tau2, const float* __restrict__ CS2,
    unsigned* __restrict__ Q2)
{
  int i = blockIdx.x * 256 + threadIdx.x;  // 32768 dwords
  if (i >= 16 * Hsz * 4) return;
  int di = i & 3, j = (i >> 2) & 511, g = i >> 11;
  int k0 = 16 * g + 4 * di;
  float ma = CS2[j];
  float r = (ma > 0.f) ? (127.f / ma) : 0.f;
  unsigned out = 0;
#pragma unroll
  for (int e = 0; e < 4; ++e) {
    int q = __float2int_rn(W_tau2[(size_t)(k0 + e) * Hsz + j] * r);
    out |= ((unsigned)(q & 255)) << (8 * e);
  }
  Q2[i] = out;
}

// zero per-batch arrival counters (must run before each scan launch)
__global__ void zero_arrive_kernel(int* __restrict__ a) { a[threadIdx.x] = 0; }

// keep a loaded uint4 pinned in VGPRs
#define KEEP4(v) asm volatile("" : "+v"((v).x), "+v"((v).y), "+v"((v).z), "+v"((v).w))

// ---------------------------------------------------------------------------
// Sequential scan, R20: 4-way K-split across CUs. 256 WGs = 64 batches x 4
// slices; wgid = s*64+b so a batch's 4 slices share an XCD under round-robin
// dispatch (perf heuristic only; correctness uses agent-scope atomics).
//
// Forensics R13-R19: the backend grants this kernel exactly the 128-VGPR
// tier; 168+ persistent regs always degraded to L2 re-streaming (~5900
// cy/step = the 2.26 ms scan). K-split shrinks per-thread persistent weights
// to 64 VGPR (drive 8 groups=32, tau2 4 groups=16, tau1 col-slice=16), which
// FITS 128 -> zero per-step weight streaming, no compiler games.
//   - tau1 is COLUMN-split (full K locally): slice s computes A[64s..64s+64)
//     entirely locally; the per-64-segment A quantization aligns exactly
//     with slice boundaries -> A needs no exchange.
//   - drive/tau2 are K-split; one 4 KB partial publish + one arrival-counter
//     sync per step; epilogue recomputed redundantly by all 4 slices with
//     fixed s'=0..3 float order -> bit-identical h everywhere (numerics
//     identical to the R2 baseline).
//   - static 56 KB LDS (mostly pad) pins the occupancy heuristic at
//     2 WGs/CU -> 128-VGPR budget (avoids R5's 64-reg trap).
// ---------------------------------------------------------------------------
__global__ __launch_bounds__(512) void scan_kernel(
    float* __restrict__ xps,           // in: xp [B,T,H]; out: hs [B,T,H]
    const float* __restrict__ U,       // [B,T,KH] (b_tau1 already added)
    const unsigned* __restrict__ Q0,   // i8 drive [32][512][4]
    const unsigned* __restrict__ Q1,   // i8 tau1  [32][256][4]
    const unsigned* __restrict__ Q2,   // i8 tau2  [16][512][4]
    const float* __restrict__ CS0,     // [512]
    const float* __restrict__ CS1,     // [256]
    const float* __restrict__ CS2,     // [512]
    const float* __restrict__ bias,    // [H]
    const float* __restrict__ b_tau2,  // [H]
    int* __restrict__ arrive,          // [64] zeroed before launch
    uint2* __restrict__ Ppart)         // [64][2][4][512] {d_int, t2_float}
{
  const int wg  = blockIdx.x;
  const int s   = wg >> 6;            // k-slice 0..3
  const int b   = wg & 63;            // batch
  const int tid = threadIdx.x;        // 0..511
  const int gq  = tid >> 6;           // tau1 k-eighth (0..7)
  const int c   = tid & 63;           // tau1 col within slice

  // 56 KB static LDS: ~4 KB used, rest pads the occupancy heuristic to
  // <=2 WGs/CU so the VGPR budget is 128 (R5: small LDS -> 64-reg budget).
  __shared__ __align__(16) unsigned char smem[57344];
  unsigned char (*Hq)[512] = (unsigned char(*)[512])(smem);     // 1024 B
  unsigned char* Aq  = smem + 1024;                             // 64 B
  float* scAp        = (float*)(smem + 1088);                   // 4 B
  int (*parti)[64]   = (int(*)[64])(smem + 1152);               // 2048 B

  const float bias_r = bias[tid];
  const float bt2_r  = b_tau2[tid];
  const float cs0r = CS0[tid] * (1.0f / 16129.0f);              // /127^2
  const float cs2r = CS2[tid] * (1.0f / 16129.0f);
  const float csr  = CS1[64 * s + c] * (1.0f / 16129.0f);
  float hold = 0.f;
  if (tid < 256) ((int*)smem)[tid] = 0;                         // zero Hq[0,1]

  float* xprow = xps + (size_t)b * Tsz * Hsz;
  const float* Urow = U + (size_t)b * Tsz * KH;

  const uint4* __restrict__ Q0u4 = (const uint4*)Q0;
  const uint4* __restrict__ Q1u4 = (const uint4*)Q1;
  const uint4* __restrict__ Q2u4 = (const uint4*)Q2;

  // --- persistent register weights (64 VGPR total) ---
  uint4 w0r[8];   // drive groups 8s..8s+7, column tid
#pragma unroll
  for (int i = 0; i < 8; ++i) w0r[i] = Q0u4[(size_t)(8 * s + i) * 512 + tid];
  uint4 w2r[4];   // tau2 groups 4s..4s+3, column tid
#pragma unroll
  for (int i = 0; i < 4; ++i) w2r[i] = Q2u4[(size_t)(4 * s + i) * 512 + tid];
  uint4 w1r[4];   // tau1 groups 4gq..4gq+3, column 64s+c
#pragma unroll
  for (int i = 0; i < 4; ++i) w1r[i] = Q1u4[(size_t)(4 * gq + i) * 256 + 64 * s + c];
#pragma unroll
  for (int i = 0; i < 8; ++i) KEEP4(w0r[i]);
#pragma unroll
  for (int i = 0; i < 4; ++i) KEEP4(w2r[i]);
#pragma unroll
  for (int i = 0; i < 4; ++i) KEEP4(w1r[i]);

  uint2* __restrict__ pub = Ppart + (size_t)b * 2 * 4 * 512;

  __syncthreads();

  // step-0 operands (subsequent steps prefetched inside the loop)
  float xpv = xprow[tid];
  float Uv  = (tid < 64) ? Urow[64 * s + tid] : 0.f;

  for (int t = 0; t < Tsz; ++t) {
    const uint4* h4 = (const uint4*)Hq[t & 1];

    // --- P1: tau1 col-slice, full K (4 reg groups/thread, 8-way k-split) ---
    int a0 = 0, a1 = 0;
#pragma unroll
    for (int i = 0; i < 4; ++i) {
      const uint4 w  = w1r[i];
      const uint4 hv = h4[4 * gq + i];                 // wave-uniform: broadcast
      a0 = dot4i8((int)w.x, (int)hv.x, a0); a1 = dot4i8((int)w.y, (int)hv.y, a1);
      a0 = dot4i8((int)w.z, (int)hv.z, a0); a1 = dot4i8((int)w.w, (int)hv.w, a1);
    }
    parti[gq][c] = a0 + a1;
    __syncthreads();                                   // bar1

    // --- P2: A slice + quantization (threads 0..63 = wave 0) ---
    if (tid < 64) {
      int sum = parti[0][tid] + parti[1][tid] + parti[2][tid] + parti[3][tid]
              + parti[4][tid] + parti[5][tid] + parti[6][tid] + parti[7][tid];
      float aval = fmaxf(Uv + (float)sum * csr, 0.f);
      float m = aval;
#pragma unroll
      for (int off = 32; off >= 1; off >>= 1)
        m = fmaxf(m, __shfl_xor(m, off));
      if (tid == 0) *scAp = m;
      const float r = (m > 0.f) ? (127.f / m) : 0.f;
      Aq[tid] = (unsigned char)__float2int_rn(aval * r);
    }
    __syncthreads();                                   // bar2

    // prefetch next-step xp/U (row t+1; slice0 overwrites row t+1 only after
    // the step-(t+1) sync, which orders after every slice's prefetch here)
    const float xpn = xprow[Hsz + tid];
    const float Un  = (tid < 64) ? Urow[KH + 64 * s + tid] : 0.f;

    // --- P3: drive k-slice + tau2 k-slice (all weights in registers) ---
    int dA = 0, dB = 0;
#pragma unroll
    for (int i = 0; i < 8; ++i) {
      const uint4 w  = w0r[i];
      const uint4 hv = h4[8 * s + i];                  // WG-uniform: broadcast
      dA = dot4i8((int)w.x, (int)hv.x, dA); dB = dot4i8((int)w.y, (int)hv.y, dB);
      dA = dot4i8((int)w.z, (int)hv.z, dA); dB = dot4i8((int)w.w, (int)hv.w, dB);
    }
    int t2a = 0, t2b = 0;
    const uint4* a4 = (const uint4*)Aq;
#pragma unroll
    for (int i = 0; i < 4; ++i) {
      const uint4 w  = w2r[i];
      const uint4 av = a4[i];
      t2a = dot4i8((int)w.x, (int)av.x, t2a); t2b = dot4i8((int)w.y, (int)av.y, t2b);
      t2a = dot4i8((int)w.z, (int)av.z, t2a); t2b = dot4i8((int)w.w, (int)av.w, t2b);
    }
    const float t2f = (float)(t2a + t2b) * cs2r * (*scAp);

    // --- publish partials + one sync round ---
    pub[((t & 1) * 4 + s) * 512 + tid] =
        make_uint2((unsigned)(dA + dB), __float_as_uint(t2f));
    __syncthreads();                                   // bar3: stores drained
    if (tid == 0) {
      __threadfence();                                 // L2 -> coherence point
      __hip_atomic_fetch_add(&arrive[b], 1, __ATOMIC_RELEASE,
                             __HIP_MEMORY_SCOPE_AGENT);
      const int target = 4 * (t + 1);
      while (__hip_atomic_load(&arrive[b], __ATOMIC_RELAXED,
                               __HIP_MEMORY_SCOPE_AGENT) < target)
        __builtin_amdgcn_s_sleep(1);
      (void)__hip_atomic_load(&arrive[b], __ATOMIC_ACQUIRE,
                              __HIP_MEMORY_SCOPE_AGENT);
    }
    __syncthreads();                                   // bar4

    // --- reduce partials (fixed s'=0..3 order: bit-identical everywhere) ---
    int dsum = 0; float ssum = bt2_r;
#pragma unroll
    for (int sp = 0; sp < 4; ++sp) {
      const unsigned long long v = __hip_atomic_load(
          (unsigned long long*)&pub[((t & 1) * 4 + sp) * 512 + tid],
          __ATOMIC_RELAXED, __HIP_MEMORY_SCOPE_AGENT);
      dsum += (int)(unsigned)v;
      ssum += __uint_as_float((unsigned)(v >> 32));
    }

    // --- epilogue (redundant in all 4 slices; deterministic) ---
    const float dd  = xpv + bias_r + (float)dsum * cs0r;
    const float tau = 5.0f + 45.0f / (1.0f + __expf(-ssum));
    const float e2  = __expf(2.0f * dd);
    const float drv = 1.0f - 2.0f / (e2 + 1.0f);       // tanh
    const float hnew = hold + (drv - hold) / tau;
    hold = hnew;
    Hq[(t + 1) & 1][tid] = (unsigned char)(__float2int_rn(hnew * 127.f) & 255);
    if (s == 0) xprow[tid] = hnew;                     // hs output
    __syncthreads();                                   // bar5: Hq ready

    xpv = xpn; Uv = Un;
    xprow += Hsz;
    Urow  += KH;
  }
}

// ---------------------------------------------------------------------------
// Epilogue: out[m,o] = hs[m,:] @ W_out[:,o] + b_out[o].
// ---------------------------------------------------------------------------
__global__ __launch_bounds__(256) void outproj_kernel(
    const float* __restrict__ hs, const float* __restrict__ W_out,
    const float* __restrict__ b_out, float* __restrict__ out)
{
  __shared__ float hsL[16][516];       // 516 = 512+4: rows spread across banks
  __shared__ float WL[Hsz * Osz];      // 20 KB
  const int tid = threadIdx.x;
  const size_t m0 = (size_t)blockIdx.x * 16;

  for (int i = tid; i < Hsz * Osz; i += 256) WL[i] = W_out[i];

  const float4* src = (const float4*)(hs + m0 * Hsz);  // 2048 float4, contiguous
#pragma unroll
  for (int i = 0; i < 8; ++i) {
    int idx = i * 256 + tid;
    *(float4*)&hsL[idx >> 7][(idx & 127) * 4] = src[idx];
  }
  __syncthreads();

  const int r = tid >> 4, o = tid & 15;
  if (o < Osz) {
    float acc = b_out[o];
#pragma unroll 8
    for (int k4 = 0; k4 < 128; ++k4) {
      const float4 h4 = *(const float4*)&hsL[r][k4 * 4];
      acc = fmaf(h4.x, WL[(4 * k4 + 0) * Osz + o], acc);
      acc = fmaf(h4.y, WL[(4 * k4 + 1) * Osz + o], acc);
      acc = fmaf(h4.z, WL[(4 * k4 + 2) * Osz + o], acc);
      acc = fmaf(h4.w, WL[(4 * k4 + 3) * Osz + o], acc);
    }
    out[(m0 + r) * Osz + o] = acc;
  }
}

// ---------------------------------------------------------------------------
extern "C" void kernel_launch(void* const* d_in, const int* in_sizes, int n_in,
                              void* d_out, int out_size, void* d_ws, size_t ws_size,
                              hipStream_t stream) {
  (void)in_sizes; (void)n_in; (void)out_size; (void)ws_size;

  const float* x      = (const float*)d_in[0];
  const float* W_in   = (const float*)d_in[1];
  const float* b_in   = (const float*)d_in[2];
  const float* W_rec  = (const float*)d_in[3];
  const float* bias   = (const float*)d_in[4];
  const float* W_tau1 = (const float*)d_in[5];
  const float* b_tau1 = (const float*)d_in[6];
  const float* W_tau2 = (const float*)d_in[7];
  const float* b_tau2 = (const float*)d_in[8];
  const float* W_out  = (const float*)d_in[9];
  const float* b_out  = (const float*)d_in[10];
  float* out = (float*)d_out;

  char* ws = (char*)d_ws;
  size_t off = 0;
  float* xps = (float*)(ws + off); off += (size_t)Bsz * Tsz * Hsz * 4;  // 128 MiB
  float* U   = (float*)(ws + off); off += (size_t)Bsz * Tsz * KH * 4;   //  64 MiB
  unsigned* Q0 = (unsigned*)(ws + off); off += (size_t)32 * Hsz * 4 * 4;// 256 KiB
  unsigned* Q1 = (unsigned*)(ws + off); off += (size_t)32 * KH  * 4 * 4;// 128 KiB
  unsigned* Q2 = (unsigned*)(ws + off); off += (size_t)16 * Hsz * 4 * 4;// 128 KiB
  float* CS0   = (float*)(ws + off); off += 512 * 4;
  float* CS1   = (float*)(ws + off); off += 256 * 4;
  float* CS2   = (float*)(ws + off); off += 512 * 4;
  float* Wc    = (float*)(ws + off); off += (size_t)Isz * KH * 4;       // 128 KiB
  float* bU    = (float*)(ws + off); off += 256 * 4;
  int*   arrive = (int*)(ws + off);  off += 1024;                        // 64 ints
  uint2* Ppart  = (uint2*)(ws + off); off += (size_t)Bsz * 2 * 4 * 512 * 8; // 2 MiB

  const float* W1a = W_tau1;                     // rows 0..511
  const float* W1b = W_tau1 + (size_t)Hsz * KH;  // rows 512..1023

  const int M = Bsz * Tsz;  // 65536

  // weight quantization + fused-U weight precompute (all small, independent)
  drive_scale_kernel<<<2, 256, 0, stream>>>(W_rec, CS0);
  drive_quant_kernel<<<256, 256, 0, stream>>>(W_rec, CS0, Q0);
  tau1_scale_kernel<<<1, 256, 0, stream>>>(W1b, CS1);
  tau1_quant_kernel<<<128, 256, 0, stream>>>(W1b, CS1, Q1);
  tau2_scale_kernel<<<2, 256, 0, stream>>>(W_tau2, CS2);
  tau2_quant_kernel<<<128, 256, 0, stream>>>(W_tau2, CS2, Q2);
  wc_kernel<<<Isz, 256, 0, stream>>>(W_in, W1a, Wc);
  bu_kernel<<<1, 256, 0, stream>>>(b_in, W1a, b_tau1, bU);

  // xp = x @ W_in + b_in            [65536,128]@[128,512]
  {
    dim3 grid(M / 64, Hsz / 128);
    gemm_bias_kernel<<<grid, 256, 0, stream>>>(x, W_in, b_in, xps, M, Hsz, Isz);
  }
  // U = x @ Wc + bU                 [65536,128]@[128,256]  (== xp@W1a + b_tau1)
  {
    dim3 grid(M / 64, KH / 128);
    gemm_bias_kernel<<<grid, 256, 0, stream>>>(x, Wc, bU, U, M, KH, Isz);
  }
  // reset arrival counters, then the K-split cooperative scan (256 WGs)
  zero_arrive_kernel<<<1, 64, 0, stream>>>(arrive);
  scan_kernel<<<256, 512, 0, stream>>>(xps, U, Q0, Q1, Q2,
                                       CS0, CS1, CS2, bias, b_tau2,
                                       arrive, Ppart);
  // output projection
  outproj_kernel<<<M / 16, 256, 0, stream>>>(xps, W_out, b_out, out);
}

// Round 9
// 2927.246 us; speedup vs baseline: 6.1390x; 6.1390x over previous
//
#include <hip/hip_runtime.h>
#include <hip/hip_fp16.h>
#include <math.h>

#define Bsz 64
#define Tsz 1024
#define Isz 128
#define Hsz 512
#define KH  256   // H/2
#define Osz 10

// ---------------------------------------------------------------------------
// Register-tiled fp32 GEMM: C[M,N] = A[M,K] @ Bw[K,N] + bias[N]
// 64x128 block tile, 8x4 micro-tile, 256 threads.
// ---------------------------------------------------------------------------
__global__ __launch_bounds__(256) void gemm_bias_kernel(
    const float* __restrict__ A, const float* __restrict__ Bw,
    const float* __restrict__ bias, float* __restrict__ C,
    int M, int N, int K)
{
  __shared__ float As[32][68];   // [k][m], padded
  const int tid = threadIdx.x;
  const int m0 = blockIdx.x * 64;
  const int n0 = blockIdx.y * 128;
  const int ty = tid >> 5, tx = tid & 31;

  float acc[8][4] = {{0.f}};

  for (int kk = 0; kk < K; kk += 32) {
    __syncthreads();
#pragma unroll
    for (int i = tid; i < 64 * 32; i += 256) {
      int m = i >> 5, k = i & 31;
      As[k][m] = A[(size_t)(m0 + m) * K + kk + k];
    }
    __syncthreads();
#pragma unroll
    for (int k = 0; k < 32; ++k) {
      const float4 bv = *(const float4*)(&Bw[(size_t)(kk + k) * N + n0 + tx * 4]);
      float a[8];
#pragma unroll
      for (int i = 0; i < 8; ++i) a[i] = As[k][ty * 8 + i];
#pragma unroll
      for (int i = 0; i < 8; ++i) {
        acc[i][0] = fmaf(a[i], bv.x, acc[i][0]);
        acc[i][1] = fmaf(a[i], bv.y, acc[i][1]);
        acc[i][2] = fmaf(a[i], bv.z, acc[i][2]);
        acc[i][3] = fmaf(a[i], bv.w, acc[i][3]);
      }
    }
  }

  const float4 bb = *(const float4*)(&bias[n0 + tx * 4]);
#pragma unroll
  for (int i = 0; i < 8; ++i) {
    float4 v;
    v.x = acc[i][0] + bb.x; v.y = acc[i][1] + bb.y;
    v.z = acc[i][2] + bb.z; v.w = acc[i][3] + bb.w;
    *(float4*)(&C[(size_t)(m0 + ty * 8 + i) * N + n0 + tx * 4]) = v;
  }
}

// ---------------------------------------------------------------------------
// Wc = W_in @ W1a  (128x512 @ 512x256 -> 128x256), one block per row i.
// ---------------------------------------------------------------------------
__global__ __launch_bounds__(256) void wc_kernel(
    const float* __restrict__ W_in, const float* __restrict__ W1a,
    float* __restrict__ Wc)
{
  __shared__ float row[Hsz];
  const int i = blockIdx.x, c = threadIdx.x;
  for (int h = c; h < Hsz; h += 256) row[h] = W_in[(size_t)i * Hsz + h];
  __syncthreads();
  float acc = 0.f;
#pragma unroll 8
  for (int h = 0; h < Hsz; ++h)
    acc = fmaf(row[h], W1a[(size_t)h * KH + c], acc);
  Wc[(size_t)i * KH + c] = acc;
}

// b_U = b_in @ W1a + b_tau1  (256)
__global__ __launch_bounds__(256) void bu_kernel(
    const float* __restrict__ b_in, const float* __restrict__ W1a,
    const float* __restrict__ b_tau1, float* __restrict__ bU)
{
  const int c = threadIdx.x;
  float acc = b_tau1[c];
#pragma unroll 8
  for (int h = 0; h < Hsz; ++h)
    acc = fmaf(b_in[h], W1a[(size_t)h * KH + c], acc);
  bU[c] = acc;
}

// ---------------------------------------------------------------------------
// i8 dot4
// ---------------------------------------------------------------------------
__device__ __forceinline__ int dot4i8(int a, int b, int acc) {
#if __has_builtin(__builtin_amdgcn_sdot4)
  return __builtin_amdgcn_sdot4(a, b, acc, false);
#else
  acc += ((a << 24) >> 24) * ((b << 24) >> 24);
  acc += ((a << 16) >> 24) * ((b << 16) >> 24);
  acc += ((a << 8)  >> 24) * ((b << 8)  >> 24);
  acc += (a >> 24) * (b >> 24);
  return acc;
#endif
}

// ---------------------------------------------------------------------------
// Quantizer layouts: [G groups x C cols] i8; group g, dword di, byte e covers
// source k = 16g + 4di + e; flat dword index = g*(C*4)+c*4+di.
// ---------------------------------------------------------------------------

// drive: col j = output row of W_rec (512 cols, 32 groups over k=512)
__global__ __launch_bounds__(256) void drive_scale_kernel(
    const float* __restrict__ W_rec, float* __restrict__ CS0)
{
  const int j = blockIdx.x * 256 + threadIdx.x;  // 512
  float m = 0.f;
  for (int k = 0; k < Hsz; ++k)
    m = fmaxf(m, fabsf(W_rec[(size_t)j * Hsz + k]));
  CS0[j] = m;
}

__global__ __launch_bounds__(256) void drive_quant_kernel(
    const float* __restrict__ W_rec, const float* __restrict__ CS0,
    unsigned* __restrict__ Q0)
{
  int i = blockIdx.x * 256 + threadIdx.x;  // 65536 dwords
  if (i >= 32 * Hsz * 4) return;
  int di = i & 3, j = (i >> 2) & 511, g = i >> 11;
  int k0 = 16 * g + 4 * di;
  float ma = CS0[j];
  float r = (ma > 0.f) ? (127.f / ma) : 0.f;
  unsigned out = 0;
#pragma unroll
  for (int e = 0; e < 4; ++e) {
    int q = __float2int_rn(W_rec[(size_t)j * Hsz + k0 + e] * r);
    out |= ((unsigned)(q & 255)) << (8 * e);
  }
  Q0[i] = out;
}

// tau1: col c (256 cols), 32 groups over j=512 (source W1b[j][c])
__global__ __launch_bounds__(256) void tau1_scale_kernel(
    const float* __restrict__ W1b, float* __restrict__ CS1)
{
  const int c = threadIdx.x;  // 256
  float m = 0.f;
  for (int j = 0; j < Hsz; ++j)
    m = fmaxf(m, fabsf(W1b[(size_t)j * KH + c]));
  CS1[c] = m;
}

__global__ __launch_bounds__(256) void tau1_quant_kernel(
    const float* __restrict__ W1b, const float* __restrict__ CS1,
    unsigned* __restrict__ Q1)
{
  int i = blockIdx.x * 256 + threadIdx.x;  // 32768 dwords
  if (i >= 32 * KH * 4) return;
  int di = i & 3, c = (i >> 2) & 255, g = i >> 10;
  int j0 = 16 * g + 4 * di;
  float ma = CS1[c];
  float r = (ma > 0.f) ? (127.f / ma) : 0.f;
  unsigned out = 0;
#pragma unroll
  for (int e = 0; e < 4; ++e) {
    int q = __float2int_rn(W1b[(size_t)(j0 + e) * KH + c] * r);
    out |= ((unsigned)(q & 255)) << (8 * e);
  }
  Q1[i] = out;
}

// tau2: col j (512 cols), 16 groups over k=256 (source W_tau2[k][j])
__global__ __launch_bounds__(256) void tau2_scale_kernel(
    const float* __restrict__ W_tau2, float* __restrict__ CS2)
{
  const int j = blockIdx.x * 256 + threadIdx.x;  // 512
  float m = 0.f;
  for (int k = 0; k < KH; ++k)
    m = fmaxf(m, fabsf(W_tau2[(size_t)k * Hsz + j]));
  CS2[j] = m;
}

__global__ __launch_bounds__(256) void tau2_quant_kernel(
    const float* __restrict__ W_tau2, const float* __restrict__ CS2,
    unsigned* __restrict__ Q2)
{
  int i = blockIdx.x * 256 + threadIdx.x;  // 32768 dwords
  if (i >= 16 * Hsz * 4) return;
  int di = i & 3, j = (i >> 2) & 511, g = i >> 11;
  int k0 = 16 * g + 4 * di;
  float ma = CS2[j];
  float r = (ma > 0.f) ? (127.f / ma) : 0.f;
  unsigned out = 0;
#pragma unroll
  for (int e = 0; e < 4; ++e) {
    int q = __float2int_rn(W_tau2[(size_t)(k0 + e) * Hsz + j] * r);
    out |= ((unsigned)(q & 255)) << (8 * e);
  }
  Q2[i] = out;
}

// keep a loaded uint4 pinned in VGPRs: the loop consumes the asm RESULT,
// which the compiler cannot rematerialize or sink back into the loop.
#define KEEP4(v) asm volatile("" : "+v"((v).x), "+v"((v).y), "+v"((v).z), "+v"((v).w))

// ---------------------------------------------------------------------------
// Sequential scan, R21: back to the proven R2 structure (512 thr, 1 WG/CU,
// scan 2263 us) with ONE change: pinned persistent demand that FITS the
// 128-VGPR tier the compiler demonstrably grants here.
//
// Forensics R13-R20: (a) allocator grants <=128 VGPRs in every config;
// (b) pinned demand > budget -> scratch spill (R3/R7); (c) per-step cross-WG
// sync costs ~17us/step (XCD write-through) -- dead; (d) scan floor =
// per-CU weight streaming: 5300 cy/step for 368 KB ==> ~71 B/cy L2->CU.
//
// This config: pin EXACTLY 64 regs (all 16 tau1 groups, KEEP4). 64 + ~50
// working < 128 -> no spill possible. LDS 152 KB = tau2 g0..15 + drive
// g28..30. Streamed: drive g0..27+g31 = 232 KB/step (-37%).
// Predicted: ~3700 cy/step -> scan ~1.6 ms.
// ---------------------------------------------------------------------------
__global__ __launch_bounds__(512) void scan_kernel(
    float* __restrict__ xps,           // in: xp [B,T,H]; out: hs [B,T,H]
    const float* __restrict__ U,       // [B,T,KH] (b_tau1 already added)
    const unsigned* __restrict__ Q0,   // i8 drive [32][512][4]
    const unsigned* __restrict__ Q1,   // i8 tau1  [32][256][4]
    const unsigned* __restrict__ Q2,   // i8 tau2  [16][512][4]
    const float* __restrict__ CS0,     // [512]
    const float* __restrict__ CS1,     // [256]
    const float* __restrict__ CS2,     // [512]
    const float* __restrict__ bias,    // [H]
    const float* __restrict__ b_tau2)  // [H]
{
  const int b = blockIdx.x;
  const int tid = threadIdx.x;
  const int hs = tid >> 8;             // tau1 k-half
  const int c  = tid & 255;            // tau1 column
  const int hs16 = hs * 16;

  extern __shared__ __align__(16) uint4 Wlds[];  // [0..8191]=tau2 g0..15
                                                 // [8192..9727]=drive g28..30
  __shared__ __align__(16) int Hq[2][128];       // i8 h, double-buffered
  __shared__ __align__(16) unsigned char Aq[KH]; // i8 A (256 B)
  __shared__ float scaleA[4];                    // per-wave A amax
  __shared__ int parti[2][KH];

  const float bias_r = bias[tid];
  const float bt2_r  = b_tau2[tid];
  const float cs0r = CS0[tid] * (1.0f / 16129.0f);  // /127^2
  const float csr  = CS1[c]   * (1.0f / 16129.0f);
  const float cs2r = CS2[tid] * (1.0f / 16129.0f);
  float hold = 0.f;
  if (tid < 128) { Hq[0][tid] = 0; Hq[1][tid] = 0; }

  float* xprow = xps + (size_t)b * Tsz * Hsz;
  const float* Urow = U + (size_t)b * Tsz * KH;

  const uint4* __restrict__ q0 = (const uint4*)Q0 + tid;                 // stride 512
  const uint4* __restrict__ q1 = (const uint4*)Q1 + (size_t)(hs * 16) * 256 + c; // stride 256
  const uint4* __restrict__ q2 = (const uint4*)Q2 + tid;                 // stride 512
  const uint4* Aq4 = (const uint4*)Aq;

  // --- one-time LDS staging: 16 tau2 groups + drive groups 28..30 ---
#pragma unroll
  for (int i = 0; i < 16; ++i)
    Wlds[i * 512 + tid] = q2[(size_t)i * 512];
#pragma unroll
  for (int i = 0; i < 3; ++i)
    Wlds[8192 + i * 512 + tid] = q0[(size_t)(28 + i) * 512];

  // --- one-time REGISTER staging: ALL 16 tau1 groups (64 VGPR, pinned) ---
  uint4 w1r[16];
#pragma unroll
  for (int g = 0; g < 16; ++g) w1r[g] = q1[(size_t)g * 256];
#pragma unroll
  for (int g = 0; g < 16; ++g) KEEP4(w1r[g]);

  __syncthreads();

  // step-0 operands (subsequent steps prefetched inside the loop)
  float xpv = xprow[tid];
  float Uv  = (tid < KH) ? Urow[tid] : 0.f;

  for (int t = 0; t < Tsz; ++t) {
    const uint4* h4 = (const uint4*)Hq[t & 1];

    // pre-issue a few streamed drive groups so their L2 latency hides
    // under P1 (pure VALU now) and P2
    const uint4 s0 = q0[(size_t)0 * 512];
    const uint4 s1 = q0[(size_t)1 * 512];
    const uint4 s2 = q0[(size_t)2 * 512];
    const uint4 s3 = q0[(size_t)3 * 512];

    // --- P1: tau1, all 16 groups from registers (pure VALU) ---
    int t1a = 0, t1b = 0;
#pragma unroll
    for (int g = 0; g < 16; ++g) {
      const uint4 w  = w1r[g];
      const uint4 hv = h4[hs16 + g];
      t1a = dot4i8((int)w.x, (int)hv.x, t1a); t1b = dot4i8((int)w.y, (int)hv.y, t1b);
      t1a = dot4i8((int)w.z, (int)hv.z, t1a); t1b = dot4i8((int)w.w, (int)hv.w, t1b);
    }
    parti[hs][c] = t1a + t1b;
    __syncthreads();                                   // sync1

    // --- P2: A + per-wave (64-lane segment) quantization ---
    if (tid < KH) {
      float aval = fmaxf(Uv + (float)(parti[0][tid] + parti[1][tid]) * csr, 0.f);
      float m = aval;
#pragma unroll
      for (int off = 32; off >= 1; off >>= 1)
        m = fmaxf(m, __shfl_xor(m, off));
      if ((tid & 63) == 0) scaleA[tid >> 6] = m;
      const float r = (m > 0.f) ? (127.f / m) : 0.f;
      Aq[tid] = (unsigned char)__float2int_rn(aval * r);
    }
    __syncthreads();                                   // sync2

    // prefetch next-step xp/U (one row ahead; last step reads into the next
    // workspace region -- mapped memory, value discarded)
    const float xpn = xprow[Hsz + tid];
    const float Un  = (tid < KH) ? Urow[KH + tid] : 0.f;

    // --- P3: drive (4 pre-issued + 24 streamed + 3 LDS + 1 streamed)
    //          fused with tau2 LDS (16 groups, flushed every 4) ---
    int dA = 0, dB = 0;
    int t2a = 0, t2b = 0;
    float s = bt2_r;
#pragma unroll
    for (int gg = 0; gg < 16; ++gg) {
      uint4 w0, w1;
      if (gg == 0)      { w0 = s0; w1 = s1; }
      else if (gg == 1) { w0 = s2; w1 = s3; }
      else if (gg < 14) {
        w0 = q0[(size_t)(2 * gg) * 512];
        w1 = q0[(size_t)(2 * gg + 1) * 512];
      } else if (gg == 14) {
        w0 = Wlds[8192 + tid];                 // g28
        w1 = Wlds[8192 + 512 + tid];           // g29
      } else {
        w0 = Wlds[8192 + 1024 + tid];          // g30
        w1 = q0[(size_t)31 * 512];             // g31 streamed
      }
      const uint4 hv0 = h4[2 * gg], hv1 = h4[2 * gg + 1];
      dA = dot4i8((int)w0.x, (int)hv0.x, dA); dB = dot4i8((int)w0.y, (int)hv0.y, dB);
      dA = dot4i8((int)w0.z, (int)hv0.z, dA); dB = dot4i8((int)w0.w, (int)hv0.w, dB);
      dA = dot4i8((int)w1.x, (int)hv1.x, dA); dB = dot4i8((int)w1.y, (int)hv1.y, dB);
      dA = dot4i8((int)w1.z, (int)hv1.z, dA); dB = dot4i8((int)w1.w, (int)hv1.w, dB);

      const uint4 wt = Wlds[gg * 512 + tid];
      const uint4 av = Aq4[gg];
      t2a = dot4i8((int)wt.x, (int)av.x, t2a); t2b = dot4i8((int)wt.y, (int)av.y, t2b);
      t2a = dot4i8((int)wt.z, (int)av.z, t2a); t2b = dot4i8((int)wt.w, (int)av.w, t2b);
      if ((gg & 3) == 3) {
        s += (float)(t2a + t2b) * cs2r * scaleA[gg >> 2];
        t2a = 0; t2b = 0;
      }
    }

    // --- epilogue: tau, tanh, Euler update ---
    const float d = xpv + bias_r + (float)(dA + dB) * cs0r;
    const float tau = 5.0f + 45.0f / (1.0f + __expf(-s));
    const float e2 = __expf(2.0f * d);
    const float drv = 1.0f - 2.0f / (e2 + 1.0f);       // tanh
    const float hnew = hold + (drv - hold) / tau;
    hold = hnew;
    ((char*)Hq[(t + 1) & 1])[tid] = (char)(__float2int_rn(hnew * 127.f) & 255);
    xprow[tid] = hnew;                                 // hs output (dead xp slot)
    __syncthreads();                                   // sync3

    xpv = xpn; Uv = Un;
    xprow += Hsz;
    Urow  += KH;
  }
}

// ---------------------------------------------------------------------------
// Epilogue: out[m,o] = hs[m,:] @ W_out[:,o] + b_out[o].
// ---------------------------------------------------------------------------
__global__ __launch_bounds__(256) void outproj_kernel(
    const float* __restrict__ hs, const float* __restrict__ W_out,
    const float* __restrict__ b_out, float* __restrict__ out)
{
  __shared__ float hsL[16][516];       // 516 = 512+4: rows spread across banks
  __shared__ float WL[Hsz * Osz];      // 20 KB
  const int tid = threadIdx.x;
  const size_t m0 = (size_t)blockIdx.x * 16;

  for (int i = tid; i < Hsz * Osz; i += 256) WL[i] = W_out[i];

  const float4* src = (const float4*)(hs + m0 * Hsz);  // 2048 float4, contiguous
#pragma unroll
  for (int i = 0; i < 8; ++i) {
    int idx = i * 256 + tid;
    *(float4*)&hsL[idx >> 7][(idx & 127) * 4] = src[idx];
  }
  __syncthreads();

  const int r = tid >> 4, o = tid & 15;
  if (o < Osz) {
    float acc = b_out[o];
#pragma unroll 8
    for (int k4 = 0; k4 < 128; ++k4) {
      const float4 h4 = *(const float4*)&hsL[r][k4 * 4];
      acc = fmaf(h4.x, WL[(4 * k4 + 0) * Osz + o], acc);
      acc = fmaf(h4.y, WL[(4 * k4 + 1) * Osz + o], acc);
      acc = fmaf(h4.z, WL[(4 * k4 + 2) * Osz + o], acc);
      acc = fmaf(h4.w, WL[(4 * k4 + 3) * Osz + o], acc);
    }
    out[(m0 + r) * Osz + o] = acc;
  }
}

// ---------------------------------------------------------------------------
extern "C" void kernel_launch(void* const* d_in, const int* in_sizes, int n_in,
                              void* d_out, int out_size, void* d_ws, size_t ws_size,
                              hipStream_t stream) {
  (void)in_sizes; (void)n_in; (void)out_size; (void)ws_size;

  const float* x      = (const float*)d_in[0];
  const float* W_in   = (const float*)d_in[1];
  const float* b_in   = (const float*)d_in[2];
  const float* W_rec  = (const float*)d_in[3];
  const float* bias   = (const float*)d_in[4];
  const float* W_tau1 = (const float*)d_in[5];
  const float* b_tau1 = (const float*)d_in[6];
  const float* W_tau2 = (const float*)d_in[7];
  const float* b_tau2 = (const float*)d_in[8];
  const float* W_out  = (const float*)d_in[9];
  const float* b_out  = (const float*)d_in[10];
  float* out = (float*)d_out;

  char* ws = (char*)d_ws;
  size_t off = 0;
  float* xps = (float*)(ws + off); off += (size_t)Bsz * Tsz * Hsz * 4;  // 128 MiB
  float* U   = (float*)(ws + off); off += (size_t)Bsz * Tsz * KH * 4;   //  64 MiB
  unsigned* Q0 = (unsigned*)(ws + off); off += (size_t)32 * Hsz * 4 * 4;// 256 KiB
  unsigned* Q1 = (unsigned*)(ws + off); off += (size_t)32 * KH  * 4 * 4;// 128 KiB
  unsigned* Q2 = (unsigned*)(ws + off); off += (size_t)16 * Hsz * 4 * 4;// 128 KiB
  float* CS0   = (float*)(ws + off); off += 512 * 4;
  float* CS1   = (float*)(ws + off); off += 256 * 4;
  float* CS2   = (float*)(ws + off); off += 512 * 4;
  float* Wc    = (float*)(ws + off); off += (size_t)Isz * KH * 4;       // 128 KiB
  float* bU    = (float*)(ws + off); off += 256 * 4;

  const float* W1a = W_tau1;                     // rows 0..511
  const float* W1b = W_tau1 + (size_t)Hsz * KH;  // rows 512..1023

  const int M = Bsz * Tsz;  // 65536

  // opt-in to 152 KB dynamic LDS for the scan kernel
  (void)hipFuncSetAttribute((const void*)scan_kernel,
                            hipFuncAttributeMaxDynamicSharedMemorySize, 155648);

  // weight quantization + fused-U weight precompute (all small, independent)
  drive_scale_kernel<<<2, 256, 0, stream>>>(W_rec, CS0);
  drive_quant_kernel<<<256, 256, 0, stream>>>(W_rec, CS0, Q0);
  tau1_scale_kernel<<<1, 256, 0, stream>>>(W1b, CS1);
  tau1_quant_kernel<<<128, 256, 0, stream>>>(W1b, CS1, Q1);
  tau2_scale_kernel<<<2, 256, 0, stream>>>(W_tau2, CS2);
  tau2_quant_kernel<<<128, 256, 0, stream>>>(W_tau2, CS2, Q2);
  wc_kernel<<<Isz, 256, 0, stream>>>(W_in, W1a, Wc);
  bu_kernel<<<1, 256, 0, stream>>>(b_in, W1a, b_tau1, bU);

  // xp = x @ W_in + b_in            [65536,128]@[128,512]
  {
    dim3 grid(M / 64, Hsz / 128);
    gemm_bias_kernel<<<grid, 256, 0, stream>>>(x, W_in, b_in, xps, M, Hsz, Isz);
  }
  // U = x @ Wc + bU                 [65536,128]@[128,256]  (== xp@W1a + b_tau1)
  {
    dim3 grid(M / 64, KH / 128);
    gemm_bias_kernel<<<grid, 256, 0, stream>>>(x, Wc, bU, U, M, KH, Isz);
  }
  // scan (64 WGs, one per batch element; 512 thr; 152 KB dynamic LDS)
  scan_kernel<<<Bsz, 512, 155648, stream>>>(xps, U, Q0, Q1, Q2,
                                            CS0, CS1, CS2, bias, b_tau2);
  // output projection
  outproj_kernel<<<M / 16, 256, 0, stream>>>(xps, W_out, b_out, out);
}